// Round 5
// baseline (907.675 us; speedup 1.0000x reference)
//
#include <hip/hip_runtime.h>
#include <cfloat>
#include <climits>

#define NEG 0.2f
#define GEPS 1e-5f
#define D 6
#define H 13   // 2*D+1
#define KOUT 16

#define MPAD 8192      // padded candidate count (atoms)
#define NRANGE 8
#define RLEN 1024      // MPAD / NRANGE
#define NBATCH 16      // RLEN / 64
#define SLOT 48        // survivor slots per thread
#define SLSTRIDE 50    // ushort stride (conflict-free)
#define SMARGIN 0.025f // s-space margin (= 0.05 in d2 space)

__device__ __forceinline__ float lrelu(float x){ return x >= 0.f ? x : NEG*x; }

__device__ __forceinline__ float rlane(float v, int l){
  return __uint_as_float(__builtin_amdgcn_readlane(__float_as_uint(v), l));
}

// descending insert of x into sorted-descending a[K] (bubble-through carry)
template<int K>
__device__ __forceinline__ void ins_desc(float (&a)[K], float x){
  #pragma unroll
  for (int t=0;t<K;++t){ float o=a[t]; bool g = x>o; a[t]=g?x:o; x=g?o:x; }
}

// ascending lexicographic insert of (d,i) into (td,ti)[K]
template<int K>
__device__ __forceinline__ void lex_insert(float (&td)[K], int (&ti)[K], float d, int i){
  bool ins = (d < td[K-1]) || (d == td[K-1] && i < ti[K-1]);
  if (ins){
    float cd = d; int ci = i;
    #pragma unroll
    for (int t=0;t<K;++t){
      bool less = (cd < td[t]) || (cd == td[t] && ci < ti[t]);
      float nd = less ? cd : td[t]; int ni = less ? ci : ti[t];
      cd = less ? td[t] : cd;       ci = less ? ti[t] : ci;
      td[t] = nd; ti[t] = ni;
    }
  }
}

// atoms (n,3) -> P {x,y,z,-0.5|c|^2} (filter space) + W {exact |c|^2}, padded
__global__ void pack_kernel(const float* __restrict__ xyz,
                            float4* __restrict__ P, float* __restrict__ W,
                            int n, int npad){
  int i = blockIdx.x*blockDim.x + threadIdx.x;
  if (i >= npad) return;
  if (i < n){
    float x = xyz[3*i], y = xyz[3*i+1], z = xyz[3*i+2];
    float sq;
    {
#pragma clang fp contract(off)
      sq = (x*x + y*y) + z*z;
    }
    P[i] = make_float4(x,y,z, -0.5f*sq);
    W[i] = sq;
  } else {
    P[i] = make_float4(0.f,0.f,0.f,-1e30f);
    W[i] = 1e30f;
  }
}

// atomtypes (n,6) -> 2-layer MLP -> out (n,6)
__global__ void tt_kernel(const float* __restrict__ at_in,
                          const float* __restrict__ w1, const float* __restrict__ b1,
                          const float* __restrict__ w2, const float* __restrict__ b2,
                          float* __restrict__ out, int n){
  int i = blockIdx.x*blockDim.x + threadIdx.x;
  if (i >= n) return;
  float x[D], h[D];
  #pragma unroll
  for (int j=0;j<D;j++) x[j] = at_in[i*D+j];
  #pragma unroll
  for (int o=0;o<D;o++){
    float acc = b1[o];
    #pragma unroll
    for (int j=0;j<D;j++) acc += w1[o*D+j]*x[j];
    h[o] = lrelu(acc);
  }
  #pragma unroll
  for (int o=0;o<D;o++){
    float acc = b2[o];
    #pragma unroll
    for (int j=0;j<D;j++) acc += w2[o*D+j]*h[j];
    out[i*D+o] = acc;
  }
}

// Per-range exact top-KSEL. Thread-per-query; candidates broadcast from
// registers via v_readlane (pure-VALU inner loop, 8 ops / 64 pairs).
// Pass 1: 32 chunk-maxes of s = dot - 0.5|c|^2 -> T = KSEL-th largest
// (32 disjoint chunks => >= KSEL distinct cands with s >= T). Pass 2:
// survivors (s >= T - margin) into private LDS slots. Phase 3: exact
// contract-off lex re-sort of survivors -> sorted (d,i)[KSEL] partials.
template<int KSEL>
__global__ __launch_bounds__(256)
void knn_range_kernel(const float4* __restrict__ candP,
                      const float*  __restrict__ candW,
                      const float*  __restrict__ qxyz, int nq,
                      float* __restrict__ pd, int* __restrict__ pi){
  __shared__ ushort sl[256][SLSTRIDE];
  const int tid  = threadIdx.x;
  const int lane = tid & 63;
  const int r    = blockIdx.y;
  const int rbase = r*RLEN;
  const int q0 = blockIdx.x*256 + tid;
  const bool qvalid = q0 < nq;
  const int q = qvalid ? q0 : (nq-1);     // clamp: keep full wave alive

  const float qx = qxyz[3*q], qy = qxyz[3*q+1], qz = qxyz[3*q+2];
  float qsq;
  {
#pragma clang fp contract(off)
    qsq = (qx*qx + qy*qy) + qz*qz;
  }

  // ---------------- pass 1: chunk maxima -> threshold ----------------
  float ch[KSEL];
  #pragma unroll
  for (int t=0;t<KSEL;t++) ch[t] = -FLT_MAX;

  for (int b = 0; b < NBATCH; ++b){
    float4 cv = candP[rbase + b*64 + lane];
    float rx=cv.x, ry=cv.y, rz=cv.z, rw=cv.w;
    float m0 = -FLT_MAX, m1 = -FLT_MAX;
    #pragma unroll
    for (int l = 0; l < 32; ++l){
      float s = fmaf(qz, rlane(rz,l), fmaf(qy, rlane(ry,l), fmaf(qx, rlane(rx,l), rlane(rw,l))));
      m0 = fmaxf(m0, s);
    }
    #pragma unroll
    for (int l = 32; l < 64; ++l){
      float s = fmaf(qz, rlane(rz,l), fmaf(qy, rlane(ry,l), fmaf(qx, rlane(rx,l), rlane(rw,l))));
      m1 = fmaxf(m1, s);
    }
    if (m0 > ch[KSEL-1]) ins_desc<KSEL>(ch, m0);
    if (m1 > ch[KSEL-1]) ins_desc<KSEL>(ch, m1);
  }
  const float Tm = ch[KSEL-1] - SMARGIN;

  // ---------------- pass 2: collect survivors ----------------
  int cnt = 0;
  for (int b = 0; b < NBATCH; ++b){
    float4 cv = candP[rbase + b*64 + lane];
    float rx=cv.x, ry=cv.y, rz=cv.z, rw=cv.w;
    const int jb = b*64;
    #pragma unroll
    for (int l = 0; l < 64; ++l){
      float s = fmaf(qz, rlane(rz,l), fmaf(qy, rlane(ry,l), fmaf(qx, rlane(rx,l), rlane(rw,l))));
      if (s >= Tm){
        if (cnt < SLOT) sl[tid][cnt] = (ushort)(jb + l);
        cnt++;
      }
    }
  }

  // ---------------- phase 3: exact lex top-KSEL ----------------
  float td[KSEL]; int ti[KSEL];
  #pragma unroll
  for (int t=0;t<KSEL;t++){ td[t] = FLT_MAX; ti[t] = INT_MAX; }

  if (cnt <= SLOT){
    for (int sI = 0; sI < cnt; ++sI){
      int g = rbase + sl[tid][sI];
      float4 cp = candP[g];
      float cw = candW[g];
      float d2;
      {
#pragma clang fp contract(off)
        float dot = qx*cp.x + qy*cp.y + qz*cp.z;
        d2 = (qsq + cw) - 2.0f*dot;
      }
      lex_insert<KSEL>(td, ti, d2, g);
    }
  } else {
    // rare fallback (threshold slot overflow): exact full rescan of range
    for (int j = 0; j < RLEN; ++j){
      int g = rbase + j;
      float4 cp = candP[g];
      float cw = candW[g];
      float d2;
      {
#pragma clang fp contract(off)
        float dot = qx*cp.x + qy*cp.y + qz*cp.z;
        d2 = (qsq + cw) - 2.0f*dot;
      }
      lex_insert<KSEL>(td, ti, d2, g);
    }
  }

  if (qvalid){
    #pragma unroll
    for (int t=0;t<KSEL;t++){
      pd[(r*KSEL + t)*nq + q0] = td[t];
      pi[(r*KSEL + t)*nq + q0] = ti[t];
    }
  }
}

// Merge NRANGE sorted partial lists -> final KOUT outputs (drop OUT_OFF head)
template<int KSEL, int OUT_OFF>
__global__ __launch_bounds__(256)
void knn_merge_kernel(const float* __restrict__ pd, const int* __restrict__ pi,
                      const float4* __restrict__ candP,
                      const float* __restrict__ qxyz, int nq,
                      int* __restrict__ oidx, float* __restrict__ odist){
  const int q = blockIdx.x*256 + threadIdx.x;
  if (q >= nq) return;
  float td[KSEL]; int ti[KSEL];
  #pragma unroll
  for (int t=0;t<KSEL;t++){ td[t] = FLT_MAX; ti[t] = INT_MAX; }
  for (int r = 0; r < NRANGE; ++r){
    for (int t = 0; t < KSEL; ++t){
      float d = pd[(r*KSEL + t)*nq + q];
      int   i = pi[(r*KSEL + t)*nq + q];
      bool ins = (d < td[KSEL-1]) || (d == td[KSEL-1] && i < ti[KSEL-1]);
      if (!ins) break;                 // range list sorted ascending lex
      lex_insert<KSEL>(td, ti, d, i);
    }
  }
  const float qx = qxyz[3*q], qy = qxyz[3*q+1], qz = qxyz[3*q+2];
  #pragma unroll
  for (int t = OUT_OFF; t < KSEL; ++t){
    int g = ti[t];
    float4 cp = candP[g];
    float dist;
    {
#pragma clang fp contract(off)
      float dx = qx-cp.x, dy = qy-cp.y, dz = qz-cp.z;
      dist = (dx*dx + dy*dy) + dz*dz;
    }
    oidx[(size_t)q*KOUT + (t-OUT_OFF)]  = g;
    odist[(size_t)q*KOUT + (t-OUT_OFF)] = dist;
  }
}

// One message-passing block: out = self + lrelu(groupnorm(sum_k MLP(feat_k)))
// 4 threads per point: each handles 4 of the 16 neighbors, shfl-reduce.
template<bool SELF_ONES>
__global__ __launch_bounds__(256)
void mp_kernel(const float* __restrict__ self_feat,
               const float* __restrict__ nb_src,
               const int* __restrict__ idx,
               const float* __restrict__ dists,
               const float* __restrict__ w1g, const float* __restrict__ b1g,
               const float* __restrict__ w2g, const float* __restrict__ b2g,
               const float* __restrict__ gam, const float* __restrict__ bet,
               float* __restrict__ out, int n){
  __shared__ float w1[H*H], b1v[H], w2[D*H], b2v[D], gm[D], bt[D];
  for (int t=threadIdx.x; t<H*H; t+=blockDim.x) w1[t]=w1g[t];
  if (threadIdx.x < H) b1v[threadIdx.x]=b1g[threadIdx.x];
  for (int t=threadIdx.x; t<D*H; t+=blockDim.x) w2[t]=w2g[t];
  if (threadIdx.x < D){
    b2v[threadIdx.x]=b2g[threadIdx.x];
    gm[threadIdx.x]=gam[threadIdx.x];
    bt[threadIdx.x]=bet[threadIdx.x];
  }
  __syncthreads();
  int tt = blockIdx.x*blockDim.x + threadIdx.x;
  int p = tt >> 2, sub = tt & 3;
  if (p >= n) return;

  float s[D];
  #pragma unroll
  for (int j=0;j<D;j++) s[j] = SELF_ONES ? 1.0f : self_feat[p*D+j];
  float msg[D] = {0,0,0,0,0,0};

  #pragma unroll
  for (int u=0;u<KOUT/4;u++){
    int k = u*4 + sub;
    int j = idx[p*KOUT+k];
    float dd = dists[p*KOUT+k];
    float f[H];
    #pragma unroll
    for (int c=0;c<D;c++) f[c]=s[c];
    #pragma unroll
    for (int c=0;c<D;c++) f[D+c]=nb_src[j*D+c];
    f[2*D]=dd;
    float h[H];
    #pragma unroll
    for (int o=0;o<H;o++){
      float acc=b1v[o];
      #pragma unroll
      for (int c=0;c<H;c++) acc += w1[o*H+c]*f[c];
      h[o]=lrelu(acc);
    }
    #pragma unroll
    for (int o=0;o<D;o++){
      float acc=b2v[o];
      #pragma unroll
      for (int c=0;c<H;c++) acc += w2[o*H+c]*h[c];
      msg[o]+=acc;
    }
  }

  #pragma unroll
  for (int c=0;c<D;c++){
    msg[c] += __shfl_xor(msg[c], 1);
    msg[c] += __shfl_xor(msg[c], 2);
  }

  if (sub == 0){
    float y[D];
    #pragma unroll
    for (int gi=0; gi<2; gi++){
      float m0=msg[gi*3+0], m1=msg[gi*3+1], m2=msg[gi*3+2];
      float mu = ((m0+m1)+m2) / 3.0f;
      float d0=m0-mu, d1=m1-mu, d2v=m2-mu;
      float var = ((d0*d0 + d1*d1) + d2v*d2v) / 3.0f;
      float inv = 1.0f / sqrtf(var + GEPS);
      y[gi*3+0] = d0*inv;
      y[gi*3+1] = d1*inv;
      y[gi*3+2] = d2v*inv;
    }
    #pragma unroll
    for (int c=0;c<D;c++){
      float vv = y[c]*gm[c] + bt[c];
      out[p*D+c] = s[c] + lrelu(vv);
    }
  }
}

extern "C" void kernel_launch(void* const* d_in, const int* in_sizes, int n_in,
                              void* d_out, int out_size, void* d_ws, size_t ws_size,
                              hipStream_t stream){
  const float* xyz       = (const float*)d_in[0];
  const float* atom_xyz  = (const float*)d_in[1];
  const float* atomtypes = (const float*)d_in[2];
  const float* tt_w1 = (const float*)d_in[5];
  const float* tt_b1 = (const float*)d_in[6];
  const float* tt_w2 = (const float*)d_in[7];
  const float* tt_b2 = (const float*)d_in[8];
  const float* aa_w1 = (const float*)d_in[9];
  const float* aa_b1 = (const float*)d_in[10];
  const float* aa_w2 = (const float*)d_in[11];
  const float* aa_b2 = (const float*)d_in[12];
  const float* aa_gamma = (const float*)d_in[13];
  const float* aa_beta  = (const float*)d_in[14];
  const float* em_w1 = (const float*)d_in[15];
  const float* em_b1 = (const float*)d_in[16];
  const float* em_w2 = (const float*)d_in[17];
  const float* em_b2 = (const float*)d_in[18];
  const float* em_gamma = (const float*)d_in[19];
  const float* em_beta  = (const float*)d_in[20];

  const int n_pts = in_sizes[0]/3;
  const int n_at  = in_sizes[1]/3;

  char* ws = (char*)d_ws;
  float4* candP = (float4*)ws; ws += (size_t)MPAD*sizeof(float4);
  float*  candW = (float*)ws;  ws += (size_t)MPAD*4;
  float* fa   = (float*)ws; ws += (size_t)n_at*D*4;
  float* fb   = (float*)ws; ws += (size_t)n_at*D*4;
  int*   idxA = (int*)ws;   ws += (size_t)n_at*KOUT*4;
  float* distA= (float*)ws; ws += (size_t)n_at*KOUT*4;
  int*   idxP = (int*)ws;   ws += (size_t)n_pts*KOUT*4;
  float* distP= (float*)ws; ws += (size_t)n_pts*KOUT*4;
  float* ea   = (float*)ws; ws += (size_t)n_pts*D*4;
  float* eb   = (float*)ws; ws += (size_t)n_pts*D*4;
  float* pdA  = (float*)ws; ws += (size_t)NRANGE*17*n_at*4;
  int*   piA  = (int*)ws;   ws += (size_t)NRANGE*17*n_at*4;
  float* pdP  = (float*)ws; ws += (size_t)NRANGE*KOUT*n_pts*4;
  int*   piP  = (int*)ws;   ws += (size_t)NRANGE*KOUT*n_pts*4;
  float* outf = (float*)d_out;

  pack_kernel<<<(MPAD+255)/256,256,0,stream>>>(atom_xyz, candP, candW, n_at, MPAD);

  tt_kernel<<<(n_at+255)/256,256,0,stream>>>(atomtypes, tt_w1,tt_b1,tt_w2,tt_b2, fa, n_at);

  // ---- atom-atom KNN (k=17, drop self) ----
  knn_range_kernel<17><<<dim3((n_at+255)/256, NRANGE),256,0,stream>>>(
      candP, candW, atom_xyz, n_at, pdA, piA);
  knn_merge_kernel<17,1><<<(n_at+255)/256,256,0,stream>>>(
      pdA, piA, candP, atom_xyz, n_at, idxA, distA);

  mp_kernel<false><<<(n_at*4+255)/256,256,0,stream>>>(fa, fa, idxA, distA,
      aa_w1+0*H*H, aa_b1+0*H, aa_w2+0*D*H, aa_b2+0*D, aa_gamma+0*D, aa_beta+0*D, fb, n_at);
  mp_kernel<false><<<(n_at*4+255)/256,256,0,stream>>>(fb, fb, idxA, distA,
      aa_w1+1*H*H, aa_b1+1*H, aa_w2+1*D*H, aa_b2+1*D, aa_gamma+1*D, aa_beta+1*D, fa, n_at);
  mp_kernel<false><<<(n_at*4+255)/256,256,0,stream>>>(fa, fa, idxA, distA,
      aa_w1+2*H*H, aa_b1+2*H, aa_w2+2*D*H, aa_b2+2*D, aa_gamma+2*D, aa_beta+2*D, fb, n_at);
  // final atom features in fb

  // ---- point-atom KNN (k=16) ----
  knn_range_kernel<16><<<dim3((n_pts+255)/256, NRANGE),256,0,stream>>>(
      candP, candW, xyz, n_pts, pdP, piP);
  knn_merge_kernel<16,0><<<(n_pts+255)/256,256,0,stream>>>(
      pdP, piP, candP, xyz, n_pts, idxP, distP);

  mp_kernel<true ><<<(n_pts*4+255)/256,256,0,stream>>>(nullptr, fb, idxP, distP,
      em_w1+0*H*H, em_b1+0*H, em_w2+0*D*H, em_b2+0*D, em_gamma+0*D, em_beta+0*D, ea, n_pts);
  mp_kernel<false><<<(n_pts*4+255)/256,256,0,stream>>>(ea, fb, idxP, distP,
      em_w1+1*H*H, em_b1+1*H, em_w2+1*D*H, em_b2+1*D, em_gamma+1*D, em_beta+1*D, eb, n_pts);
  mp_kernel<false><<<(n_pts*4+255)/256,256,0,stream>>>(eb, fb, idxP, distP,
      em_w1+2*H*H, em_b1+2*H, em_w2+2*D*H, em_b2+2*D, em_gamma+2*D, em_beta+2*D, outf, n_pts);
}